// Round 13
// baseline (132.844 us; speedup 1.0000x reference)
//
#include <hip/hip_runtime.h>
#include <hip/hip_bf16.h>
#include <math.h>
#include <stdint.h>

#define N_    8
#define CH    256
#define CL    512
#define NECK  64
#define H_    128
#define W_    128
#define HW    16384
#define HWS   1024
#define EPSB  1e-5f
#define SC31  (31.0f/127.0f)

typedef unsigned short ushort_t;
typedef __attribute__((ext_vector_type(8))) short bf16x8;
typedef __attribute__((ext_vector_type(4))) float f32x4;

union bfpack  { ushort_t u[8]; bf16x8 v; };

__device__ __forceinline__ float sigmoidf_(float x){ return 1.0f/(1.0f + __expf(-x)); }

__device__ __forceinline__ ushort_t f2bf(float x){
    union { __hip_bfloat16 h; ushort_t u; } cv;
    cv.h = __float2bfloat16(x);              // RNE; pairs fuse to v_cvt_pk_bf16_f32
    return cv.u;
}
__device__ __forceinline__ uint32_t pack2(float lo, float hi){
    return (uint32_t)f2bf(lo) | ((uint32_t)f2bf(hi) << 16);
}
__device__ __forceinline__ float bf2f(ushort_t b){
    union { uint32_t u; float f; } v; v.u = ((uint32_t)b) << 16;
    return v.f;
}

__device__ __forceinline__ void gload16(const void* g, void* l){
    __builtin_amdgcn_global_load_lds((const __attribute__((address_space(1))) void*)g,
                                     (__attribute__((address_space(3))) void*)l, 16, 0, 0);
}

// ---------------- K0: staging launch, 512 thr, grid 2152
// blocks 0..63     : small conv MFMA  C[128][px] = Wk[128][512] * Xo[512][px]
// blocks 64..79    : wz pack -> Wzb bf16
// blocks 80..103   : wv1/wq1/wq2 pack -> Wbig bf16 [192][256]
// blocks 104..2151 : transpose+convert x[8][256][16384] f32 -> XT[8][16384][256] bf16 (in d_out!)
__global__ __launch_bounds__(512) void k_stage(
    const float* __restrict__ x, const float* __restrict__ xo,
    const float* __restrict__ wv1, const float* __restrict__ wq1, const float* __restrict__ wq2,
    const float* __restrict__ wk1, const float* __restrict__ wk2,
    const float* __restrict__ sk1, const float* __restrict__ bk1,
    const float* __restrict__ sk2, const float* __restrict__ bk2,
    const float* __restrict__ wz,
    ushort_t* __restrict__ XT,
    float* __restrict__ k1s, float* __restrict__ k2s,
    ushort_t* __restrict__ Wzb, ushort_t* __restrict__ Wbig)
{
    __shared__ __align__(16) char smem[36864];
    int blk = blockIdx.x;
    int t = threadIdx.x;

    if (blk >= 104){
        // ---- transpose tile: 64 ch x 256 px, LDS [256p][72c-stride]
        ushort_t* tile = (ushort_t*)smem;          // 256*72*2 = 36KB
        int tb = blk - 104;
        int n = tb >> 8;
        int r = tb & 255;
        int cb = (r >> 6) << 6;                    // 4 ch-tiles
        int pb = (r & 63) << 8;                    // 64 px-tiles
        int lane = t & 63, w8 = t >> 6;
        const float* s = x + ((size_t)n*CH + cb)*HW + pb;
        // phase 1: coalesced 256B loads (lane = px), uint2 LDS column writes
        #pragma unroll
        for (int i=0;i<4;i++){
            int c0 = i*16 + w8*2;                  // c-pair per wave
            #pragma unroll
            for (int pp=0;pp<4;pp++){
                int p = pp*64 + lane;
                float v0 = s[(size_t)c0*HW + p];
                float v1 = s[(size_t)(c0+1)*HW + p];
                *(uint32_t*)&tile[p*72 + c0] = pack2(v0, v1);
            }
        }
        __syncthreads();
        // phase 2: uint4 LDS row reads; stores = 8 lanes x 16B = one full 128B line per p
        #pragma unroll
        for (int pass=0; pass<4; ++pass){
            int p = pass*64 + (t>>3);
            int c8 = (t&7)*8;
            uint4 v = *(const uint4*)&tile[p*72 + c8];
            *(uint4*)(XT + ((size_t)n*HW + pb + p)*CH + cb + c8) = v;
        }
        return;
    }

    if (blk >= 80){
        // ---- Wbig pack: [192][256] rows wv1,wq1,wq2 (24 blocks)
        int e = (blk - 80)*2048 + t*4;             // 0..49151
        int o = e >> 8, c = e & 255;
        const float* w = (o < 64) ? (wv1 + (size_t)o*CH)
                       : (o < 128) ? (wq1 + (size_t)(o-64)*CH)
                                   : (wq2 + (size_t)(o-128)*CH);
        float4 f = *(const float4*)(w + c);
        *(uint2*)(Wbig + e) = make_uint2(pack2(f.x,f.y), pack2(f.z,f.w));
        return;
    }
    if (blk >= 64){
        // ---- wz pack (16 blocks)
        int i = (blk - 64)*2048 + t*4;
        float4 f = *(const float4*)(wz + i);
        *(uint2*)(Wzb + i) = make_uint2(pack2(f.x,f.y), pack2(f.z,f.w));
        return;
    }

    // ---- small conv MFMA: BM=128(o), BN=128(px), BK=64, 8 K-steps  (blocks 0..63)
    {
        ushort_t* At = (ushort_t*)smem;            // [128][64] swizzled, 16KB
        ushort_t* Bt = (ushort_t*)(smem + 16384);  // [128][64] swizzled, 16KB
        int lane = t & 63, w8 = t >> 6;
        int wm = w8 >> 1, wn = w8 & 1;
        int r16 = lane & 15;
        float inv = rsqrtf(1.0f + EPSB);
        int b = blk;
        int n = b >> 3, pix0 = (b & 7) << 7;
        f32x4 acc[2][4];
        #pragma unroll
        for (int m=0;m<2;m++)
            #pragma unroll
            for (int nn=0;nn<4;nn++) acc[m][nn] = (f32x4){0.f,0.f,0.f,0.f};

        const float* xb = xo + (size_t)n*CL*HWS + pix0;
        float va[8], vb[8];
        {
            const float* xc = xb + (size_t)(8*w8)*HWS;
            #pragma unroll
            for (int j=0;j<8;j++){
                va[j] = xc[(size_t)j*HWS + lane];
                vb[j] = xc[(size_t)j*HWS + 64 + lane];
            }
        }
        int oo = t >> 3, c8 = t & 7;
        for (int kt=0; kt<8; ++kt){
            int c0 = kt*64;
            const float* ws0 = wk1 + (size_t)oo*CL + c0 + c8*8;
            const float* ws1 = wk2 + (size_t)oo*CL + c0 + c8*8;
            float4 a00 = *(const float4*)ws0, a01 = *(const float4*)(ws0+4);
            float4 a10 = *(const float4*)ws1, a11 = *(const float4*)(ws1+4);
            uint32_t pa[4], pb[4];
            #pragma unroll
            for (int j=0;j<4;j++){
                pa[j] = pack2(va[2*j], va[2*j+1]);
                pb[j] = pack2(vb[2*j], vb[2*j+1]);
            }
            int offA = (lane*128 + w8*16) ^ ((lane&7)<<4);
            int offB = ((lane+64)*128 + w8*16) ^ ((lane&7)<<4);
            *(uint4*)((char*)Bt + offA) = make_uint4(pa[0],pa[1],pa[2],pa[3]);
            *(uint4*)((char*)Bt + offB) = make_uint4(pb[0],pb[1],pb[2],pb[3]);
            {
                int off0 = (oo*128 + c8*16) ^ ((oo&7)<<4);
                int off1 = ((64+oo)*128 + c8*16) ^ ((oo&7)<<4);
                *(uint4*)((char*)At + off0) = make_uint4(pack2(a00.x,a00.y),pack2(a00.z,a00.w),
                                                         pack2(a01.x,a01.y),pack2(a01.z,a01.w));
                *(uint4*)((char*)At + off1) = make_uint4(pack2(a10.x,a10.y),pack2(a10.z,a10.w),
                                                         pack2(a11.x,a11.y),pack2(a11.z,a11.w));
            }
            __syncthreads();
            if (kt < 7){
                const float* xc = xb + (size_t)((kt+1)*64 + 8*w8)*HWS;
                #pragma unroll
                for (int j=0;j<8;j++){
                    va[j] = xc[(size_t)j*HWS + lane];
                    vb[j] = xc[(size_t)j*HWS + 64 + lane];
                }
            }
            #pragma unroll
            for (int ks=0; ks<2; ++ks){
                bf16x8 a[2], bfr[4];
                #pragma unroll
                for (int m=0;m<2;m++){
                    int row = wm*32 + m*16 + r16;
                    int off = (row*128 + ks*64 + (lane>>4)*16) ^ ((row&7)<<4);
                    a[m] = *(const bf16x8*)((const char*)At + off);
                }
                #pragma unroll
                for (int nn=0;nn<4;nn++){
                    int row = wn*64 + nn*16 + r16;
                    int off = (row*128 + ks*64 + (lane>>4)*16) ^ ((row&7)<<4);
                    bfr[nn] = *(const bf16x8*)((const char*)Bt + off);
                }
                #pragma unroll
                for (int m=0;m<2;m++)
                    #pragma unroll
                    for (int nn=0;nn<4;nn++)
                        acc[m][nn] = __builtin_amdgcn_mfma_f32_16x16x32_bf16(a[m], bfr[nn], acc[m][nn], 0, 0, 0);
            }
            __syncthreads();
        }
        #pragma unroll
        for (int m=0;m<2;m++){
            int obase = wm*32 + m*16 + ((lane>>4)<<2);
            #pragma unroll
            for (int r=0;r<4;r++){
                int o = obase + r;
                int oc = o & 63;
                float sc = ((o<64) ? sk1[oc] : sk2[oc]) * inv;
                float bb =  (o<64) ? bk1[oc] : bk2[oc];
                float* dst = ((o<64) ? k1s : k2s) + ((size_t)n*NECK + oc)*HWS + pix0;
                #pragma unroll
                for (int nn=0;nn<4;nn++){
                    int px = wn*64 + nn*16 + r16;
                    dst[px] = fmaxf(fmaf(acc[m][nn][r], sc, bb), 0.f);
                }
            }
        }
    }
}

// ---------------- K1: bf16 MFMA GEMM: C[192][pix] = Wbig * XT^T
// B staged in LDS (16KB) via global_load_lds; A-fragments read DIRECTLY from
// Wbig (96KB, L2-resident) — same pattern k_final_mfma uses for Wzb.
__global__ __launch_bounds__(512) void k_gemm_big(
    const ushort_t* __restrict__ XT,   // [8][16384][256] bf16
    const ushort_t* __restrict__ Wb,   // [192][256] bf16
    const float* __restrict__ s1, const float* __restrict__ b1,
    const float* __restrict__ s2, const float* __restrict__ b2,
    ushort_t* __restrict__ value, ushort_t* __restrict__ query, ushort_t* __restrict__ query2)
{
    __shared__ ushort_t Bt[128*64];    // 16KB (swizzled)
    int blk = blockIdx.x;              // 1024 = 8 img * 128 px-tiles
    int n = blk >> 7;
    int pix0 = (blk & 127) << 7;
    int t = threadIdx.x;
    int wid = t >> 6, lane = t & 63;
    int wm = wid >> 1, wn = wid & 1;   // wave tile 48 x 64

    f32x4 acc[3][4];
    #pragma unroll
    for (int m=0;m<3;m++)
        #pragma unroll
        for (int nn=0;nn<4;nn++) acc[m][nn] = (f32x4){0.f,0.f,0.f,0.f};

    // A-fragment base pointers (bf16 weights, L2-hot)
    const ushort_t* abase[3];
    #pragma unroll
    for (int m=0;m<3;m++){
        int row = wm*48 + m*16 + (lane&15);
        abase[m] = Wb + (size_t)row*CH + (lane>>4)*8;
    }

    const ushort_t* Xb = XT + ((size_t)n*HW + pix0)*CH;
    for (int kt=0; kt<4; ++kt){
        int c0 = kt*64;
        // issue B staging (async -> LDS)
        #pragma unroll
        for (int i=0;i<2;i++){
            int g = i*512 + t;
            int s = g ^ ((g>>3)&7);
            gload16(Xb + (size_t)(s>>3)*CH + c0 + (s&7)*8, (char*)Bt + g*16);
        }
        // load A fragments for both ks while B flies
        bf16x8 a[2][3];
        #pragma unroll
        for (int ks=0; ks<2; ++ks)
            #pragma unroll
            for (int m=0;m<3;m++)
                a[ks][m] = *(const bf16x8*)(abase[m] + c0 + ks*32);
        __syncthreads();
        #pragma unroll
        for (int ks=0; ks<2; ++ks){
            bf16x8 b[4];
            #pragma unroll
            for (int nn=0;nn<4;nn++){
                int row = wn*64 + nn*16 + (lane&15);
                int off = (row*128 + ks*64 + (lane>>4)*16) ^ ((row&7)<<4);
                b[nn] = *(const bf16x8*)((const char*)Bt + off);
            }
            #pragma unroll
            for (int m=0;m<3;m++)
                #pragma unroll
                for (int nn=0;nn<4;nn++)
                    acc[m][nn] = __builtin_amdgcn_mfma_f32_16x16x32_bf16(a[ks][m], b[nn], acc[m][nn], 0, 0, 0);
        }
        __syncthreads();
    }
    float inv = rsqrtf(1.0f + EPSB);
    #pragma unroll
    for (int m=0;m<3;m++){
        int obase = wm*48 + m*16 + ((lane>>4)<<2);
        #pragma unroll
        for (int r=0;r<4;r++){
            int o = obase + r;
            int grp = o >> 6, oc = o & 63;
            float sc = 1.f, bb = 0.f;
            ushort_t* dst;
            if (grp == 0) dst = value;
            else if (grp == 1){ sc = s1[oc]*inv; bb = b1[oc]; dst = query; }
            else              { sc = s2[oc]*inv; bb = b2[oc]; dst = query2; }
            #pragma unroll
            for (int nn=0;nn<4;nn++){
                int pix = pix0 + wn*64 + nn*16 + (lane&15);
                float v = acc[m][nn][r];
                if (grp) v = fmaxf(fmaf(v, sc, bb), 0.f);
                dst[((size_t)(n*NECK + oc))*HW + pix] = f2bf(v);
            }
        }
    }
}

// ---------------- K3: MFMA gates. blocks 0..255 scale-1, 256..511 scale-2. 256 thr.
__global__ __launch_bounds__(256) void k_gates(
    const ushort_t* __restrict__ query, const float* __restrict__ k1small,
    float* __restrict__ gate1, float* __restrict__ gate2)
{
    __shared__ __align__(16) char smem[69632];   // ksm 4K | qt 32K | kt 32K  (pw/simM alias front)
    int bid = blockIdx.x;
    int t = threadIdx.x;
    int lane = t & 63, wv = t >> 6;
    int r16 = lane & 15, g = lane >> 4;
    float* ksm = (float*)smem;
    ushort_t* qt = (ushort_t*)(smem + 4096);
    ushort_t* kt = (ushort_t*)(smem + 4096 + 32768);

    if (bid < 256){
        int n = bid >> 5, c = bid & 31;
        const float* ks = k1small + (size_t)(n*NECK + c)*HWS;
        #pragma unroll
        for (int i=0;i<4;i++) ksm[i*256+t] = ks[i*256+t];
        __syncthreads();
        const ushort_t* qb = query + (size_t)(n*NECK + c)*HW;
        #pragma unroll
        for (int i=0;i<8;i++){
            int task = i*256 + t;
            int p = task >> 7, c8 = task & 127;
            int ly = c8 >> 2, lx8 = (c8 & 3)*8;
            int h = (p>>2)*32 + ly, w = (p&3)*32 + lx8;
            bf16x8 qv = *(const bf16x8*)(qb + h*W_ + w);
            int off = (p*2048 + c8*16) ^ ((p&7)<<4);
            *(bf16x8*)((char*)qt + off) = qv;
            float yf = h*SC31; int y0=(int)yf; int y1=min(y0+1,31); float fy=yf-(float)y0;
            bfpack pk;
            #pragma unroll
            for (int j=0;j<8;j++){
                int ww = w + j;
                float xf = ww*SC31; int x0=(int)xf; int x1=min(x0+1,31); float fx=xf-(float)x0;
                float a=ksm[y0*32+x0], b=ksm[y0*32+x1], cc=ksm[y1*32+x0], d=ksm[y1*32+x1];
                float r0=a+(b-a)*fx, r1=cc+(d-cc)*fx;
                pk.u[j] = f2bf(r0 + (r1-r0)*fy);
            }
            *(bf16x8*)((char*)kt + off) = pk.v;
        }
        __syncthreads();
        f32x4 acc = (f32x4){0.f,0.f,0.f,0.f};
        #pragma unroll
        for (int k8=0; k8<8; ++k8){
            int l0 = wv*256 + k8*32 + g*8;
            int off = (r16*2048 + l0*2) ^ ((r16&7)<<4);
            bf16x8 av = *(const bf16x8*)((char*)qt + off);
            bf16x8 bv = *(const bf16x8*)((char*)kt + off);
            acc = __builtin_amdgcn_mfma_f32_16x16x32_bf16(av, bv, acc, 0, 0, 0);
        }
        __syncthreads();
        float* pw = (float*)smem;             // [4][256]
        #pragma unroll
        for (int r=0;r<4;r++)
            pw[wv*256 + (g*4+r)*16 + r16] = acc[r];
        __syncthreads();
        float* simM = (float*)(smem + 4096);  // [256]
        float s = pw[t] + pw[256+t] + pw[512+t] + pw[768+t];
        simM[t] = sigmoidf_(s);
        __syncthreads();
        if (t < 16){
            float rs=0.f, cs=0.f;
            #pragma unroll
            for (int q=0;q<16;q++) rs += simM[t*16+q];
            #pragma unroll
            for (int p=0;p<16;p++) cs += simM[p*16+t];
            gate1[(size_t)(n*32 + c)*16 + t] = (rs + cs) * (1.0f/16.0f);
        }
    } else {
        int b2 = bid - 256;
        int n = b2 >> 5, cl = b2 & 31, c = 32 + cl;
        const float* ks = k1small + (size_t)(n*NECK + c)*HWS;
        #pragma unroll
        for (int i=0;i<4;i++) ksm[i*256+t] = ks[i*256+t];
        __syncthreads();
        const ushort_t* qb = query + (size_t)(n*NECK + c)*HW;
        #pragma unroll
        for (int i=0;i<8;i++){
            int task = i*256 + t;
            int p = task >> 5, c8 = task & 31;
            int ly = c8 >> 1, lx8 = (c8 & 1)*8;
            int h = (p>>3)*16 + ly, w = (p&7)*16 + lx8;
            bf16x8 qv = *(const bf16x8*)(qb + h*W_ + w);
            int off = (p*512 + c8*16) ^ ((p&7)<<4);
            *(bf16x8*)((char*)qt + off) = qv;
            float yf = h*SC31; int y0=(int)yf; int y1=min(y0+1,31); float fy=yf-(float)y0;
            bfpack pk;
            #pragma unroll
            for (int j=0;j<8;j++){
                int ww = w + j;
                float xf = ww*SC31; int x0=(int)xf; int x1=min(x0+1,31); float fx=xf-(float)x0;
                float a=ksm[y0*32+x0], b=ksm[y0*32+x1], cc=ksm[y1*32+x0], d=ksm[y1*32+x1];
                float r0=a+(b-a)*fx, r1=cc+(d-cc)*fx;
                pk.u[j] = f2bf(r0 + (r1-r0)*fy);
            }
            *(bf16x8*)((char*)kt + off) = pk.v;
        }
        __syncthreads();
        f32x4 acc2[4];
        #pragma unroll
        for (int qc=0;qc<4;qc++) acc2[qc] = (f32x4){0.f,0.f,0.f,0.f};
        #pragma unroll
        for (int k8=0; k8<8; ++k8){
            int l0 = k8*32 + g*8;
            int offA = ((wv*16 + r16)*512 + l0*2) ^ ((r16&7)<<4);
            bf16x8 av = *(const bf16x8*)((char*)qt + offA);
            #pragma unroll
            for (int qc=0;qc<4;qc++){
                int offB = ((qc*16 + r16)*512 + l0*2) ^ ((r16&7)<<4);
                bf16x8 bv = *(const bf16x8*)((char*)kt + offB);
                acc2[qc] = __builtin_amdgcn_mfma_f32_16x16x32_bf16(av, bv, acc2[qc], 0, 0, 0);
            }
        }
        __syncthreads();
        float* simM = (float*)smem;           // [64][65]
        #pragma unroll
        for (int qc=0;qc<4;qc++)
            #pragma unroll
            for (int r=0;r<4;r++){
                int p = wv*16 + g*4 + r, q = qc*16 + r16;
                simM[p*65 + q] = sigmoidf_(acc2[qc][r]);
            }
        __syncthreads();
        if (t < 64){
            float rs=0.f, cs=0.f;
            for (int q=0;q<64;q++) rs += simM[t*65 + q];
            for (int p=0;p<64;p++) cs += simM[p*65 + t];
            gate2[(size_t)(n*32 + cl)*64 + t] = (rs + cs) * (1.0f/64.0f);
        }
    }
}

// ---------------- K4: context build + final conv via bf16 MFMA (A direct from global)
__global__ __launch_bounds__(512, 4) void k_final_mfma(
    const ushort_t* __restrict__ value, const ushort_t* __restrict__ query2,
    const float* __restrict__ k2small,
    const float* __restrict__ gate1, const float* __restrict__ gate2,
    const ushort_t* __restrict__ Wzb,
    const float* __restrict__ alpha_p, const float* __restrict__ gamma_p,
    float* __restrict__ out)
{
    __shared__ __align__(16) char smem[59392];  // Ct 32K | g1s 2K | g2s 8K | k2r 16K
    ushort_t* Ct = (ushort_t*)smem;
    float* g1s = (float*)(smem + 32768);
    float* g2s = (float*)(smem + 34816);
    float* k2r = (float*)(smem + 43008);
    int blk = blockIdx.x;
    int n = blk >> 7, h = blk & 127;
    int pix0 = h << 7;
    int t = threadIdx.x;
    int lane = t & 63;
    int wid = t >> 6;
    int wm = wid >> 1, wn = wid & 1;

    int px = t & 127, qd = t >> 7;
    const size_t vbase = (size_t)n*NECK*HW + pix0 + px;
    ushort_t vreg[16], qreg[16];
    #pragma unroll
    for (int i=0;i<16;i++){
        int c = qd*16 + i;
        vreg[i] = value [vbase + (size_t)c*HW];
        qreg[i] = query2[vbase + (size_t)c*HW];
    }

    float alpha = alpha_p[0], gamma = gamma_p[0];
    g1s[t & 511] = gate1[(size_t)n*512 + (t & 511)];
    #pragma unroll
    for (int i=0;i<4;i++) g2s[i*512 + t] = gate2[(size_t)n*2048 + i*512 + t];

    float yf = h * SC31;
    int y0 = (int)yf, y1 = min(y0+1, 31);
    float fy = yf - (float)y0;
    #pragma unroll
    for (int i=0;i<8;i++){
        int e = i*512 + t;
        int buf = e >> 11, c = (e >> 5) & 63, xx = e & 31;
        k2r[buf*2048 + c*32 + xx] = k2small[((size_t)n*NECK + c)*HWS + (buf ? y1 : y0)*32 + xx];
    }
    __syncthreads();

    float xf = px * SC31;
    int x0 = (int)xf, x1 = min(x0+1, 31);
    float fx = xf - (float)x0;
    int patch1 = (h>>5)*4 + (px>>5);
    int patch2 = (h>>4)*8 + (px>>4);
    #pragma unroll
    for (int j=0;j<2;j++){
        bfpack pk;
        #pragma unroll
        for (int i=0;i<8;i++){
            int ch = qd*16 + j*8 + i;
            float g = (ch < 32) ? g1s[ch*16 + patch1] : g2s[(ch-32)*64 + patch2];
            pk.u[i] = f2bf(alpha * g * bf2f(vreg[j*8+i]));
        }
        int off = (px*256 + qd*32 + j*16) ^ ((px&7)<<4);
        *(bf16x8*)((char*)Ct + off) = pk.v;
    }
    #pragma unroll
    for (int j=0;j<2;j++){
        bfpack pk;
        #pragma unroll
        for (int i=0;i<8;i++){
            int c = qd*16 + j*8 + i;
            float vv = bf2f(vreg[j*8+i]);
            float q2 = bf2f(qreg[j*8+i]);
            float r0 = k2r[c*32+x0];      r0 += (k2r[c*32+x1] - r0)*fx;
            float r1 = k2r[2048+c*32+x0]; r1 += (k2r[2048+c*32+x1] - r1)*fx;
            float kv = r0 + (r1 - r0)*fy;
            pk.u[i] = f2bf(gamma * vv * sigmoidf_(q2*kv));
        }
        int off = (px*256 + 128 + qd*32 + j*16) ^ ((px&7)<<4);
        *(bf16x8*)((char*)Ct + off) = pk.v;
    }
    __syncthreads();

    f32x4 acc[4][4];
    #pragma unroll
    for (int m=0;m<4;m++)
        #pragma unroll
        for (int nn=0;nn<4;nn++) acc[m][nn] = (f32x4){0.f,0.f,0.f,0.f};
    #pragma unroll
    for (int ks=0; ks<4; ++ks){
        bf16x8 a[4], b[4];
        #pragma unroll
        for (int m=0;m<4;m++){
            int row = wm*64 + m*16 + (lane&15);
            a[m] = *(const bf16x8*)(Wzb + row*128 + ks*32 + (lane>>4)*8);
        }
        #pragma unroll
        for (int nn=0;nn<4;nn++){
            int row = wn*64 + nn*16 + (lane&15);
            int off = (row*256 + ks*64 + (lane>>4)*16) ^ ((row&7)<<4);
            b[nn] = *(const bf16x8*)((const char*)Ct + off);
        }
        #pragma unroll
        for (int m=0;m<4;m++)
            #pragma unroll
            for (int nn=0;nn<4;nn++)
                acc[m][nn] = __builtin_amdgcn_mfma_f32_16x16x32_bf16(a[m], b[nn], acc[m][nn], 0, 0, 0);
    }

    #pragma unroll
    for (int m=0;m<4;m++){
        int obase = wm*64 + m*16 + ((lane>>4)<<2);
        #pragma unroll
        for (int r=0;r<4;r++){
            int o = obase + r;
            float* dst = out + ((size_t)(n*CH + o))*HW + pix0 + wn*64 + (lane&15);
            #pragma unroll
            for (int nn=0;nn<4;nn++)
                dst[nn*16] = acc[m][nn][r];
        }
    }
}

extern "C" void kernel_launch(void* const* d_in, const int* in_sizes, int n_in,
                              void* d_out, int out_size, void* d_ws, size_t ws_size,
                              hipStream_t stream) {
    const float* x0  = (const float*)d_in[0];
    const float* xo  = (const float*)d_in[1];
    const float* wq1 = (const float*)d_in[2];
    const float* s1  = (const float*)d_in[3];
    const float* b1  = (const float*)d_in[4];
    const float* wk1 = (const float*)d_in[5];
    const float* sk1 = (const float*)d_in[6];
    const float* bk1 = (const float*)d_in[7];
    const float* wv1 = (const float*)d_in[8];
    const float* wq2 = (const float*)d_in[9];
    const float* s2  = (const float*)d_in[10];
    const float* b2  = (const float*)d_in[11];
    const float* wk2 = (const float*)d_in[12];
    const float* sk2 = (const float*)d_in[13];
    const float* bk2 = (const float*)d_in[14];
    const float* wz  = (const float*)d_in[15];
    const float* alp = (const float*)d_in[16];
    const float* gam = (const float*)d_in[17];

    // workspace layout (~55 MB); XT (67 MB bf16) aliases d_out (134 MB f32,
    // fully overwritten by k_final afterwards; written-before-read every call).
    ushort_t* value  = (ushort_t*)d_ws;          // 8*64*16384
    ushort_t* query  = value  + 8388608;
    ushort_t* query2 = query  + 8388608;
    float*    k1s    = (float*)(query2 + 8388608);
    float*    k2s    = k1s + 524288;
    float*    g1     = k2s + 524288;
    float*    g2     = g1 + 4096;
    ushort_t* Wzb    = (ushort_t*)(g2 + 16384);  // 256*128
    ushort_t* Wbig   = Wzb + 32768;              // 192*256
    ushort_t* XT     = (ushort_t*)d_out;         // 8*16384*256 bf16

    k_stage<<<dim3(2152), dim3(512), 0, stream>>>(
        x0, xo, wv1, wq1, wq2, wk1, wk2, sk1, bk1, sk2, bk2, wz,
        XT, k1s, k2s, Wzb, Wbig);
    k_gemm_big<<<dim3(1024), dim3(512), 0, stream>>>(
        XT, Wbig, s1, b1, s2, b2, value, query, query2);
    k_gates<<<dim3(512), dim3(256), 0, stream>>>(query, k1s, g1, g2);
    k_final_mfma<<<dim3(1024), dim3(512), 0, stream>>>(value, query2, k2s, g1, g2, Wzb,
                                                       alp, gam, (float*)d_out);
}

// Round 14
// 125.097 us; speedup vs baseline: 1.0619x; 1.0619x over previous
//
#include <hip/hip_runtime.h>
#include <hip/hip_bf16.h>
#include <math.h>
#include <stdint.h>

#define N_    8
#define CH    256
#define CL    512
#define NECK  64
#define H_    128
#define W_    128
#define HW    16384
#define HWS   1024
#define EPSB  1e-5f
#define SC31  (31.0f/127.0f)

typedef unsigned short ushort_t;
typedef __attribute__((ext_vector_type(8))) short bf16x8;
typedef __attribute__((ext_vector_type(4))) float f32x4;

union bfpack  { ushort_t u[8]; bf16x8 v; };

__device__ __forceinline__ float sigmoidf_(float x){ return 1.0f/(1.0f + __expf(-x)); }

__device__ __forceinline__ ushort_t f2bf(float x){
    union { __hip_bfloat16 h; ushort_t u; } cv;
    cv.h = __float2bfloat16(x);              // RNE; pairs fuse to v_cvt_pk_bf16_f32
    return cv.u;
}
__device__ __forceinline__ uint32_t pack2(float lo, float hi){
    return (uint32_t)f2bf(lo) | ((uint32_t)f2bf(hi) << 16);
}
__device__ __forceinline__ float bf2f(ushort_t b){
    union { uint32_t u; float f; } v; v.u = ((uint32_t)b) << 16;
    return v.f;
}

__device__ __forceinline__ void gload16(const void* g, void* l){
    __builtin_amdgcn_global_load_lds((const __attribute__((address_space(1))) void*)g,
                                     (__attribute__((address_space(3))) void*)l, 16, 0, 0);
}

// ---------------- K0: staging launch, 512 thr, grid 2152
// blocks 0..63     : small conv MFMA  C[128][px] = Wk[128][512] * Xo[512][px]
// blocks 64..79    : wz pack -> Wzb bf16
// blocks 80..103   : wv1/wq1/wq2 pack -> Wbig bf16 [192][256]
// blocks 104..2151 : transpose+convert x[8][256][16384] f32 -> XT[8][16384][256] bf16 (in d_out!)
//                    LDS tile [p][66-stride]: odd word-stride -> conflict-free u32 writes (2-way).
__global__ __launch_bounds__(512) void k_stage(
    const float* __restrict__ x, const float* __restrict__ xo,
    const float* __restrict__ wv1, const float* __restrict__ wq1, const float* __restrict__ wq2,
    const float* __restrict__ wk1, const float* __restrict__ wk2,
    const float* __restrict__ sk1, const float* __restrict__ bk1,
    const float* __restrict__ sk2, const float* __restrict__ bk2,
    const float* __restrict__ wz,
    ushort_t* __restrict__ XT,
    float* __restrict__ k1s, float* __restrict__ k2s,
    ushort_t* __restrict__ Wzb, ushort_t* __restrict__ Wbig)
{
    __shared__ __align__(16) char smem[33792];
    int blk = blockIdx.x;
    int t = threadIdx.x;

    if (blk >= 104){
        // ---- transpose tile: 64 ch x 256 px, LDS [256p][66c-stride u16]
        ushort_t* tile = (ushort_t*)smem;          // 256*66*2 = 33792B
        int tb = blk - 104;
        int n = tb >> 8;
        int r = tb & 255;
        int cb = (r >> 6) << 6;                    // 4 ch-tiles
        int pb = (r & 63) << 8;                    // 64 px-tiles
        int lane = t & 63, w8 = t >> 6;
        const float* s = x + ((size_t)n*CH + cb)*HW + pb;
        // phase 1: coalesced 256B loads (lane = px), u32 LDS writes (banks p%32 -> 2-way free)
        #pragma unroll
        for (int i=0;i<4;i++){
            int c0 = i*16 + w8*2;                  // c-pair per wave
            #pragma unroll
            for (int pp=0;pp<4;pp++){
                int p = pp*64 + lane;
                float v0 = s[(size_t)c0*HW + p];
                float v1 = s[(size_t)(c0+1)*HW + p];
                *(uint32_t*)&tile[p*66 + c0] = pack2(v0, v1);
            }
        }
        __syncthreads();
        // phase 2: 4x u32 LDS reads (≈2-way), assemble uint4, store full 128B lines
        #pragma unroll
        for (int pass=0; pass<4; ++pass){
            int p = pass*64 + (t>>3);
            int c8 = (t&7)*8;
            uint32_t w0 = *(const uint32_t*)&tile[p*66 + c8    ];
            uint32_t w1 = *(const uint32_t*)&tile[p*66 + c8 + 2];
            uint32_t w2 = *(const uint32_t*)&tile[p*66 + c8 + 4];
            uint32_t w3 = *(const uint32_t*)&tile[p*66 + c8 + 6];
            *(uint4*)(XT + ((size_t)n*HW + pb + p)*CH + cb + c8) = make_uint4(w0,w1,w2,w3);
        }
        return;
    }

    if (blk >= 80){
        // ---- Wbig pack: [192][256] rows wv1,wq1,wq2 (24 blocks)
        int e = (blk - 80)*2048 + t*4;             // 0..49151
        int o = e >> 8, c = e & 255;
        const float* w = (o < 64) ? (wv1 + (size_t)o*CH)
                       : (o < 128) ? (wq1 + (size_t)(o-64)*CH)
                                   : (wq2 + (size_t)(o-128)*CH);
        float4 f = *(const float4*)(w + c);
        *(uint2*)(Wbig + e) = make_uint2(pack2(f.x,f.y), pack2(f.z,f.w));
        return;
    }
    if (blk >= 64){
        // ---- wz pack (16 blocks)
        int i = (blk - 64)*2048 + t*4;
        float4 f = *(const float4*)(wz + i);
        *(uint2*)(Wzb + i) = make_uint2(pack2(f.x,f.y), pack2(f.z,f.w));
        return;
    }

    // ---- small conv MFMA: BM=128(o), BN=128(px), BK=64, 8 K-steps  (blocks 0..63)
    {
        ushort_t* At = (ushort_t*)smem;            // [128][64] swizzled, 16KB
        ushort_t* Bt = (ushort_t*)(smem + 16384);  // [128][64] swizzled, 16KB
        int lane = t & 63, w8 = t >> 6;
        int wm = w8 >> 1, wn = w8 & 1;
        int r16 = lane & 15;
        float inv = rsqrtf(1.0f + EPSB);
        int b = blk;
        int n = b >> 3, pix0 = (b & 7) << 7;
        f32x4 acc[2][4];
        #pragma unroll
        for (int m=0;m<2;m++)
            #pragma unroll
            for (int nn=0;nn<4;nn++) acc[m][nn] = (f32x4){0.f,0.f,0.f,0.f};

        const float* xb = xo + (size_t)n*CL*HWS + pix0;
        float va[8], vb[8];
        {
            const float* xc = xb + (size_t)(8*w8)*HWS;
            #pragma unroll
            for (int j=0;j<8;j++){
                va[j] = xc[(size_t)j*HWS + lane];
                vb[j] = xc[(size_t)j*HWS + 64 + lane];
            }
        }
        int oo = t >> 3, c8 = t & 7;
        for (int kt=0; kt<8; ++kt){
            int c0 = kt*64;
            const float* ws0 = wk1 + (size_t)oo*CL + c0 + c8*8;
            const float* ws1 = wk2 + (size_t)oo*CL + c0 + c8*8;
            float4 a00 = *(const float4*)ws0, a01 = *(const float4*)(ws0+4);
            float4 a10 = *(const float4*)ws1, a11 = *(const float4*)(ws1+4);
            uint32_t pa[4], pb[4];
            #pragma unroll
            for (int j=0;j<4;j++){
                pa[j] = pack2(va[2*j], va[2*j+1]);
                pb[j] = pack2(vb[2*j], vb[2*j+1]);
            }
            int offA = (lane*128 + w8*16) ^ ((lane&7)<<4);
            int offB = ((lane+64)*128 + w8*16) ^ ((lane&7)<<4);
            *(uint4*)((char*)Bt + offA) = make_uint4(pa[0],pa[1],pa[2],pa[3]);
            *(uint4*)((char*)Bt + offB) = make_uint4(pb[0],pb[1],pb[2],pb[3]);
            {
                int off0 = (oo*128 + c8*16) ^ ((oo&7)<<4);
                int off1 = ((64+oo)*128 + c8*16) ^ ((oo&7)<<4);
                *(uint4*)((char*)At + off0) = make_uint4(pack2(a00.x,a00.y),pack2(a00.z,a00.w),
                                                         pack2(a01.x,a01.y),pack2(a01.z,a01.w));
                *(uint4*)((char*)At + off1) = make_uint4(pack2(a10.x,a10.y),pack2(a10.z,a10.w),
                                                         pack2(a11.x,a11.y),pack2(a11.z,a11.w));
            }
            __syncthreads();
            if (kt < 7){
                const float* xc = xb + (size_t)((kt+1)*64 + 8*w8)*HWS;
                #pragma unroll
                for (int j=0;j<8;j++){
                    va[j] = xc[(size_t)j*HWS + lane];
                    vb[j] = xc[(size_t)j*HWS + 64 + lane];
                }
            }
            #pragma unroll
            for (int ks=0; ks<2; ++ks){
                bf16x8 a[2], bfr[4];
                #pragma unroll
                for (int m=0;m<2;m++){
                    int row = wm*32 + m*16 + r16;
                    int off = (row*128 + ks*64 + (lane>>4)*16) ^ ((row&7)<<4);
                    a[m] = *(const bf16x8*)((const char*)At + off);
                }
                #pragma unroll
                for (int nn=0;nn<4;nn++){
                    int row = wn*64 + nn*16 + r16;
                    int off = (row*128 + ks*64 + (lane>>4)*16) ^ ((row&7)<<4);
                    bfr[nn] = *(const bf16x8*)((const char*)Bt + off);
                }
                #pragma unroll
                for (int m=0;m<2;m++)
                    #pragma unroll
                    for (int nn=0;nn<4;nn++)
                        acc[m][nn] = __builtin_amdgcn_mfma_f32_16x16x32_bf16(a[m], bfr[nn], acc[m][nn], 0, 0, 0);
            }
            __syncthreads();
        }
        #pragma unroll
        for (int m=0;m<2;m++){
            int obase = wm*32 + m*16 + ((lane>>4)<<2);
            #pragma unroll
            for (int r=0;r<4;r++){
                int o = obase + r;
                int oc = o & 63;
                float sc = ((o<64) ? sk1[oc] : sk2[oc]) * inv;
                float bb =  (o<64) ? bk1[oc] : bk2[oc];
                float* dst = ((o<64) ? k1s : k2s) + ((size_t)n*NECK + oc)*HWS + pix0;
                #pragma unroll
                for (int nn=0;nn<4;nn++){
                    int px = wn*64 + nn*16 + r16;
                    dst[px] = fmaxf(fmaf(acc[m][nn][r], sc, bb), 0.f);
                }
            }
        }
    }
}

// ---------------- K1: bf16 MFMA GEMM (round-12 structure, proven best):
// C[192][pix] = Wbig * XT^T ; BM=192, BN=128, BK=64; global_load_lds both operands.
__global__ __launch_bounds__(512) void k_gemm_big(
    const ushort_t* __restrict__ XT,   // [8][16384][256] bf16
    const ushort_t* __restrict__ Wb,   // [192][256] bf16
    const float* __restrict__ s1, const float* __restrict__ b1,
    const float* __restrict__ s2, const float* __restrict__ b2,
    ushort_t* __restrict__ value, ushort_t* __restrict__ query, ushort_t* __restrict__ query2)
{
    __shared__ ushort_t At[192*64];    // 24KB (swizzled)
    __shared__ ushort_t Bt[128*64];    // 16KB (swizzled)
    int blk = blockIdx.x;              // 1024 = 8 img * 128 px-tiles
    int n = blk >> 7;
    int pix0 = (blk & 127) << 7;
    int t = threadIdx.x;
    int wid = t >> 6, lane = t & 63;
    int wm = wid >> 1, wn = wid & 1;   // wave tile 48 x 64

    f32x4 acc[3][4];
    #pragma unroll
    for (int m=0;m<3;m++)
        #pragma unroll
        for (int nn=0;nn<4;nn++) acc[m][nn] = (f32x4){0.f,0.f,0.f,0.f};

    const ushort_t* Xb = XT + ((size_t)n*HW + pix0)*CH;
    for (int kt=0; kt<4; ++kt){
        int c0 = kt*64;
        #pragma unroll
        for (int i=0;i<3;i++){
            int g = i*512 + t;
            int s = g ^ ((g>>3)&7);
            gload16(Wb + (size_t)(s>>3)*CH + c0 + (s&7)*8, (char*)At + g*16);
        }
        #pragma unroll
        for (int i=0;i<2;i++){
            int g = i*512 + t;
            int s = g ^ ((g>>3)&7);
            gload16(Xb + (size_t)(s>>3)*CH + c0 + (s&7)*8, (char*)Bt + g*16);
        }
        __syncthreads();
        #pragma unroll
        for (int ks=0; ks<2; ++ks){
            bf16x8 a[3], b[4];
            #pragma unroll
            for (int m=0;m<3;m++){
                int row = wm*48 + m*16 + (lane&15);
                int off = (row*128 + ks*64 + (lane>>4)*16) ^ ((row&7)<<4);
                a[m] = *(const bf16x8*)((const char*)At + off);
            }
            #pragma unroll
            for (int nn=0;nn<4;nn++){
                int row = wn*64 + nn*16 + (lane&15);
                int off = (row*128 + ks*64 + (lane>>4)*16) ^ ((row&7)<<4);
                b[nn] = *(const bf16x8*)((const char*)Bt + off);
            }
            #pragma unroll
            for (int m=0;m<3;m++)
                #pragma unroll
                for (int nn=0;nn<4;nn++)
                    acc[m][nn] = __builtin_amdgcn_mfma_f32_16x16x32_bf16(a[m], b[nn], acc[m][nn], 0, 0, 0);
        }
        __syncthreads();
    }
    float inv = rsqrtf(1.0f + EPSB);
    #pragma unroll
    for (int m=0;m<3;m++){
        int obase = wm*48 + m*16 + ((lane>>4)<<2);
        #pragma unroll
        for (int r=0;r<4;r++){
            int o = obase + r;
            int grp = o >> 6, oc = o & 63;
            float sc = 1.f, bb = 0.f;
            ushort_t* dst;
            if (grp == 0) dst = value;
            else if (grp == 1){ sc = s1[oc]*inv; bb = b1[oc]; dst = query; }
            else              { sc = s2[oc]*inv; bb = b2[oc]; dst = query2; }
            #pragma unroll
            for (int nn=0;nn<4;nn++){
                int pix = pix0 + wn*64 + nn*16 + (lane&15);
                float v = acc[m][nn][r];
                if (grp) v = fmaxf(fmaf(v, sc, bb), 0.f);
                dst[((size_t)(n*NECK + oc))*HW + pix] = f2bf(v);
            }
        }
    }
}

// ---------------- K3: MFMA gates. blocks 0..255 scale-1, 256..511 scale-2. 256 thr.
__global__ __launch_bounds__(256) void k_gates(
    const ushort_t* __restrict__ query, const float* __restrict__ k1small,
    float* __restrict__ gate1, float* __restrict__ gate2)
{
    __shared__ __align__(16) char smem[69632];   // ksm 4K | qt 32K | kt 32K  (pw/simM alias front)
    int bid = blockIdx.x;
    int t = threadIdx.x;
    int lane = t & 63, wv = t >> 6;
    int r16 = lane & 15, g = lane >> 4;
    float* ksm = (float*)smem;
    ushort_t* qt = (ushort_t*)(smem + 4096);
    ushort_t* kt = (ushort_t*)(smem + 4096 + 32768);

    if (bid < 256){
        int n = bid >> 5, c = bid & 31;
        const float* ks = k1small + (size_t)(n*NECK + c)*HWS;
        #pragma unroll
        for (int i=0;i<4;i++) ksm[i*256+t] = ks[i*256+t];
        __syncthreads();
        const ushort_t* qb = query + (size_t)(n*NECK + c)*HW;
        #pragma unroll
        for (int i=0;i<8;i++){
            int task = i*256 + t;
            int p = task >> 7, c8 = task & 127;
            int ly = c8 >> 2, lx8 = (c8 & 3)*8;
            int h = (p>>2)*32 + ly, w = (p&3)*32 + lx8;
            bf16x8 qv = *(const bf16x8*)(qb + h*W_ + w);
            int off = (p*2048 + c8*16) ^ ((p&7)<<4);
            *(bf16x8*)((char*)qt + off) = qv;
            float yf = h*SC31; int y0=(int)yf; int y1=min(y0+1,31); float fy=yf-(float)y0;
            bfpack pk;
            #pragma unroll
            for (int j=0;j<8;j++){
                int ww = w + j;
                float xf = ww*SC31; int x0=(int)xf; int x1=min(x0+1,31); float fx=xf-(float)x0;
                float a=ksm[y0*32+x0], b=ksm[y0*32+x1], cc=ksm[y1*32+x0], d=ksm[y1*32+x1];
                float r0=a+(b-a)*fx, r1=cc+(d-cc)*fx;
                pk.u[j] = f2bf(r0 + (r1-r0)*fy);
            }
            *(bf16x8*)((char*)kt + off) = pk.v;
        }
        __syncthreads();
        f32x4 acc = (f32x4){0.f,0.f,0.f,0.f};
        #pragma unroll
        for (int k8=0; k8<8; ++k8){
            int l0 = wv*256 + k8*32 + g*8;
            int off = (r16*2048 + l0*2) ^ ((r16&7)<<4);
            bf16x8 av = *(const bf16x8*)((char*)qt + off);
            bf16x8 bv = *(const bf16x8*)((char*)kt + off);
            acc = __builtin_amdgcn_mfma_f32_16x16x32_bf16(av, bv, acc, 0, 0, 0);
        }
        __syncthreads();
        float* pw = (float*)smem;             // [4][256]
        #pragma unroll
        for (int r=0;r<4;r++)
            pw[wv*256 + (g*4+r)*16 + r16] = acc[r];
        __syncthreads();
        float* simM = (float*)(smem + 4096);  // [256]
        float s = pw[t] + pw[256+t] + pw[512+t] + pw[768+t];
        simM[t] = sigmoidf_(s);
        __syncthreads();
        if (t < 16){
            float rs=0.f, cs=0.f;
            #pragma unroll
            for (int q=0;q<16;q++) rs += simM[t*16+q];
            #pragma unroll
            for (int p=0;p<16;p++) cs += simM[p*16+t];
            gate1[(size_t)(n*32 + c)*16 + t] = (rs + cs) * (1.0f/16.0f);
        }
    } else {
        int b2 = bid - 256;
        int n = b2 >> 5, cl = b2 & 31, c = 32 + cl;
        const float* ks = k1small + (size_t)(n*NECK + c)*HWS;
        #pragma unroll
        for (int i=0;i<4;i++) ksm[i*256+t] = ks[i*256+t];
        __syncthreads();
        const ushort_t* qb = query + (size_t)(n*NECK + c)*HW;
        #pragma unroll
        for (int i=0;i<8;i++){
            int task = i*256 + t;
            int p = task >> 5, c8 = task & 31;
            int ly = c8 >> 1, lx8 = (c8 & 1)*8;
            int h = (p>>3)*16 + ly, w = (p&7)*16 + lx8;
            bf16x8 qv = *(const bf16x8*)(qb + h*W_ + w);
            int off = (p*512 + c8*16) ^ ((p&7)<<4);
            *(bf16x8*)((char*)qt + off) = qv;
            float yf = h*SC31; int y0=(int)yf; int y1=min(y0+1,31); float fy=yf-(float)y0;
            bfpack pk;
            #pragma unroll
            for (int j=0;j<8;j++){
                int ww = w + j;
                float xf = ww*SC31; int x0=(int)xf; int x1=min(x0+1,31); float fx=xf-(float)x0;
                float a=ksm[y0*32+x0], b=ksm[y0*32+x1], cc=ksm[y1*32+x0], d=ksm[y1*32+x1];
                float r0=a+(b-a)*fx, r1=cc+(d-cc)*fx;
                pk.u[j] = f2bf(r0 + (r1-r0)*fy);
            }
            *(bf16x8*)((char*)kt + off) = pk.v;
        }
        __syncthreads();
        f32x4 acc2[4];
        #pragma unroll
        for (int qc=0;qc<4;qc++) acc2[qc] = (f32x4){0.f,0.f,0.f,0.f};
        #pragma unroll
        for (int k8=0; k8<8; ++k8){
            int l0 = k8*32 + g*8;
            int offA = ((wv*16 + r16)*512 + l0*2) ^ ((r16&7)<<4);
            bf16x8 av = *(const bf16x8*)((char*)qt + offA);
            #pragma unroll
            for (int qc=0;qc<4;qc++){
                int offB = ((qc*16 + r16)*512 + l0*2) ^ ((r16&7)<<4);
                bf16x8 bv = *(const bf16x8*)((char*)kt + offB);
                acc2[qc] = __builtin_amdgcn_mfma_f32_16x16x32_bf16(av, bv, acc2[qc], 0, 0, 0);
            }
        }
        __syncthreads();
        float* simM = (float*)smem;           // [64][65]
        #pragma unroll
        for (int qc=0;qc<4;qc++)
            #pragma unroll
            for (int r=0;r<4;r++){
                int p = wv*16 + g*4 + r, q = qc*16 + r16;
                simM[p*65 + q] = sigmoidf_(acc2[qc][r]);
            }
        __syncthreads();
        if (t < 64){
            float rs=0.f, cs=0.f;
            for (int q=0;q<64;q++) rs += simM[t*65 + q];
            for (int p=0;p<64;p++) cs += simM[p*65 + t];
            gate2[(size_t)(n*32 + cl)*64 + t] = (rs + cs) * (1.0f/64.0f);
        }
    }
}

// ---------------- K4: context build + final conv via bf16 MFMA (A direct from global)
__global__ __launch_bounds__(512, 4) void k_final_mfma(
    const ushort_t* __restrict__ value, const ushort_t* __restrict__ query2,
    const float* __restrict__ k2small,
    const float* __restrict__ gate1, const float* __restrict__ gate2,
    const ushort_t* __restrict__ Wzb,
    const float* __restrict__ alpha_p, const float* __restrict__ gamma_p,
    float* __restrict__ out)
{
    __shared__ __align__(16) char smem[59392];  // Ct 32K | g1s 2K | g2s 8K | k2r 16K
    ushort_t* Ct = (ushort_t*)smem;
    float* g1s = (float*)(smem + 32768);
    float* g2s = (float*)(smem + 34816);
    float* k2r = (float*)(smem + 43008);
    int blk = blockIdx.x;
    int n = blk >> 7, h = blk & 127;
    int pix0 = h << 7;
    int t = threadIdx.x;
    int lane = t & 63;
    int wid = t >> 6;
    int wm = wid >> 1, wn = wid & 1;

    int px = t & 127, qd = t >> 7;
    const size_t vbase = (size_t)n*NECK*HW + pix0 + px;
    ushort_t vreg[16], qreg[16];
    #pragma unroll
    for (int i=0;i<16;i++){
        int c = qd*16 + i;
        vreg[i] = value [vbase + (size_t)c*HW];
        qreg[i] = query2[vbase + (size_t)c*HW];
    }

    float alpha = alpha_p[0], gamma = gamma_p[0];
    g1s[t & 511] = gate1[(size_t)n*512 + (t & 511)];
    #pragma unroll
    for (int i=0;i<4;i++) g2s[i*512 + t] = gate2[(size_t)n*2048 + i*512 + t];

    float yf = h * SC31;
    int y0 = (int)yf, y1 = min(y0+1, 31);
    float fy = yf - (float)y0;
    #pragma unroll
    for (int i=0;i<8;i++){
        int e = i*512 + t;
        int buf = e >> 11, c = (e >> 5) & 63, xx = e & 31;
        k2r[buf*2048 + c*32 + xx] = k2small[((size_t)n*NECK + c)*HWS + (buf ? y1 : y0)*32 + xx];
    }
    __syncthreads();

    float xf = px * SC31;
    int x0 = (int)xf, x1 = min(x0+1, 31);
    float fx = xf - (float)x0;
    int patch1 = (h>>5)*4 + (px>>5);
    int patch2 = (h>>4)*8 + (px>>4);
    #pragma unroll
    for (int j=0;j<2;j++){
        bfpack pk;
        #pragma unroll
        for (int i=0;i<8;i++){
            int ch = qd*16 + j*8 + i;
            float g = (ch < 32) ? g1s[ch*16 + patch1] : g2s[(ch-32)*64 + patch2];
            pk.u[i] = f2bf(alpha * g * bf2f(vreg[j*8+i]));
        }
        int off = (px*256 + qd*32 + j*16) ^ ((px&7)<<4);
        *(bf16x8*)((char*)Ct + off) = pk.v;
    }
    #pragma unroll
    for (int j=0;j<2;j++){
        bfpack pk;
        #pragma unroll
        for (int i=0;i<8;i++){
            int c = qd*16 + j*8 + i;
            float vv = bf2f(vreg[j*8+i]);
            float q2 = bf2f(qreg[j*8+i]);
            float r0 = k2r[c*32+x0];      r0 += (k2r[c*32+x1] - r0)*fx;
            float r1 = k2r[2048+c*32+x0]; r1 += (k2r[2048+c*32+x1] - r1)*fx;
            float kv = r0 + (r1 - r0)*fy;
            pk.u[i] = f2bf(gamma * vv * sigmoidf_(q2*kv));
        }
        int off = (px*256 + 128 + qd*32 + j*16) ^ ((px&7)<<4);
        *(bf16x8*)((char*)Ct + off) = pk.v;
    }
    __syncthreads();

    f32x4 acc[4][4];
    #pragma unroll
    for (int m=0;m<4;m++)
        #pragma unroll
        for (int nn=0;nn<4;nn++) acc[m][nn] = (f32x4){0.f,0.f,0.f,0.f};
    #pragma unroll
    for (int ks=0; ks<4; ++ks){
        bf16x8 a[4], b[4];
        #pragma unroll
        for (int m=0;m<4;m++){
            int row = wm*64 + m*16 + (lane&15);
            a[m] = *(const bf16x8*)(Wzb + row*128 + ks*32 + (lane>>4)*8);
        }
        #pragma unroll
        for (int nn=0;nn<4;nn++){
            int row = wn*64 + nn*16 + (lane&15);
            int off = (row*256 + ks*64 + (lane>>4)*16) ^ ((row&7)<<4);
            b[nn] = *(const bf16x8*)((const char*)Ct + off);
        }
        #pragma unroll
        for (int m=0;m<4;m++)
            #pragma unroll
            for (int nn=0;nn<4;nn++)
                acc[m][nn] = __builtin_amdgcn_mfma_f32_16x16x32_bf16(a[m], b[nn], acc[m][nn], 0, 0, 0);
    }

    #pragma unroll
    for (int m=0;m<4;m++){
        int obase = wm*64 + m*16 + ((lane>>4)<<2);
        #pragma unroll
        for (int r=0;r<4;r++){
            int o = obase + r;
            float* dst = out + ((size_t)(n*CH + o))*HW + pix0 + wn*64 + (lane&15);
            #pragma unroll
            for (int nn=0;nn<4;nn++)
                dst[nn*16] = acc[m][nn][r];
        }
    }
}

extern "C" void kernel_launch(void* const* d_in, const int* in_sizes, int n_in,
                              void* d_out, int out_size, void* d_ws, size_t ws_size,
                              hipStream_t stream) {
    const float* x0  = (const float*)d_in[0];
    const float* xo  = (const float*)d_in[1];
    const float* wq1 = (const float*)d_in[2];
    const float* s1  = (const float*)d_in[3];
    const float* b1  = (const float*)d_in[4];
    const float* wk1 = (const float*)d_in[5];
    const float* sk1 = (const float*)d_in[6];
    const float* bk1 = (const float*)d_in[7];
    const float* wv1 = (const float*)d_in[8];
    const float* wq2 = (const float*)d_in[9];
    const float* s2  = (const float*)d_in[10];
    const float* b2  = (const float*)d_in[11];
    const float* wk2 = (const float*)d_in[12];
    const float* sk2 = (const float*)d_in[13];
    const float* bk2 = (const float*)d_in[14];
    const float* wz  = (const float*)d_in[15];
    const float* alp = (const float*)d_in[16];
    const float* gam = (const float*)d_in[17];

    // workspace layout (~55 MB); XT (67 MB bf16) aliases d_out (134 MB f32,
    // fully overwritten by k_final afterwards; written-before-read every call).
    ushort_t* value  = (ushort_t*)d_ws;          // 8*64*16384
    ushort_t* query  = value  + 8388608;
    ushort_t* query2 = query  + 8388608;
    float*    k1s    = (float*)(query2 + 8388608);
    float*    k2s    = k1s + 524288;
    float*    g1     = k2s + 524288;
    float*    g2     = g1 + 4096;
    ushort_t* Wzb    = (ushort_t*)(g2 + 16384);  // 256*128
    ushort_t* Wbig   = Wzb + 32768;              // 192*256
    ushort_t* XT     = (ushort_t*)d_out;         // 8*16384*256 bf16

    k_stage<<<dim3(2152), dim3(512), 0, stream>>>(
        x0, xo, wv1, wq1, wq2, wk1, wk2, sk1, bk1, sk2, bk2, wz,
        XT, k1s, k2s, Wzb, Wbig);
    k_gemm_big<<<dim3(1024), dim3(512), 0, stream>>>(
        XT, Wbig, s1, b1, s2, b2, value, query, query2);
    k_gates<<<dim3(512), dim3(256), 0, stream>>>(query, k1s, g1, g2);
    k_final_mfma<<<dim3(1024), dim3(512), 0, stream>>>(value, query2, k2s, g1, g2, Wzb,
                                                       alp, gam, (float*)d_out);
}